// Round 7
// baseline (590.607 us; speedup 1.0000x reference)
//
#include <hip/hip_runtime.h>

typedef short bf16x8 __attribute__((ext_vector_type(8)));
typedef float f32x4 __attribute__((ext_vector_type(4)));

#define MFMA16(a, b, c) __builtin_amdgcn_mfma_f32_16x16x32_bf16(a, b, c, 0, 0, 0)

constexpr int Bn = 4, Sn = 4096, En = 1024, Hn = 128;
constexpr float CSCALE = 1.44269504089f * 0.03125f;   // log2(e) * E^-0.5

__device__ inline unsigned short f2bf(float f) {
    unsigned int u = __builtin_bit_cast(unsigned int, f);
    u += 0x7fff + ((u >> 16) & 1);
    return (unsigned short)(u >> 16);
}

__device__ inline unsigned int pk2(float a, float b) {
    unsigned int ua = __builtin_bit_cast(unsigned int, a) + 0x8000u;
    unsigned int ub = __builtin_bit_cast(unsigned int, b) + 0x8000u;
    return __builtin_amdgcn_perm(ub, ua, 0x07060302u);
}

__device__ inline void gld16(const unsigned short* g, unsigned short* l) {
    __builtin_amdgcn_global_load_lds((const __attribute__((address_space(1))) void*)g,
                                     (__attribute__((address_space(3))) void*)l, 16, 0, 0);
}

// partial-slot base: qt uses ceil((qt+1)/32) slots; base = prefix sum (a=qt>>5, r=qt&31)
__device__ inline int slot_base(int qt) {
    int a = qt >> 5, r = qt & 31;
    return qt + 16 * a * (a - 1) + r * a;
}
constexpr int SLOTS_PER_B = 320;          // slot_base(128)
constexpr int SLOT_F = 4160;              // 32*128 O + 32 m + 32 l floats

// ---------------- prep: W fp32 -> bf16, [q,k,v][h][E] ----------------
__global__ __launch_bounds__(256) void prep_kernel(
    const float* __restrict__ Wk, const float* __restrict__ Wq, const float* __restrict__ Wv,
    unsigned short* __restrict__ wb)
{
    int gy = blockIdx.x >> 5;
    const float* src = (gy == 0) ? Wq : (gy == 1) ? Wk : Wv;
    unsigned short* dst = wb + (size_t)gy * Hn * En;
    int t = (blockIdx.x & 31) * 256 + threadIdx.x;
    const float4* s4 = (const float4*)src;
    for (int i = 0; i < 4; ++i) {
        float4 v = s4[(size_t)t * 4 + i];
        uint2 w2 = { pk2(v.x, v.y), pk2(v.z, v.w) };
        *(uint2*)&dst[(size_t)t * 16 + i * 4] = w2;
    }
}

// ---------------- QKV projection: async W staging (bf16), 1 barrier/kc ----------------
// grid (BS/64, 3), block 256 (4 waves; wave tile 32rows x 64h). BK=64.
// LDS unpadded + XOR-swizzled chunks (global_load_lds-compatible). 48 KB -> 3 blocks/CU.
__global__ __launch_bounds__(256, 3) void proj_kernel(
    const float* __restrict__ x, const unsigned short* __restrict__ wb,
    unsigned short* __restrict__ qb, unsigned short* __restrict__ kb,
    unsigned short* __restrict__ vbT)
{
    __shared__ __align__(16) unsigned short xs[2][64][64];    // 16 KB
    __shared__ __align__(16) unsigned short wsm[2][128][64];  // 32 KB

    const int gy = blockIdx.y;
    const unsigned short* wg = wb + (size_t)gy * Hn * En;

    const int m0 = blockIdx.x * 64;
    const int tid = threadIdx.x;
    const int lane = tid & 63, wave = tid >> 6;
    const int l15 = lane & 15, quad = lane >> 4;
    const int wm = (wave & 1) * 32;
    const int wn = (wave >> 1) * 64;

    f32x4 acc[2][4] = {};
    float4 xp[4];

    auto loadx = [&](int kc) {
        for (int p4 = 0; p4 < 4; ++p4) {
            int i = p4 * 256 + tid, row = i >> 4, c4 = (i & 15) * 4;
            xp[p4] = *(const float4*)&x[(size_t)(m0 + row) * En + kc * 64 + c4];
        }
    };
    auto writex = [&](int c) {
        for (int p4 = 0; p4 < 4; ++p4) {
            int i = p4 * 256 + tid, row = i >> 4, hc = i & 15;
            uint2 w2 = { pk2(xp[p4].x, xp[p4].y), pk2(xp[p4].z, xp[p4].w) };
            *(uint2*)((char*)&xs[c][0][0] + row * 128 + (((hc >> 1) ^ (row & 7)) << 4) + ((hc & 1) << 3)) = w2;
        }
    };
    auto issueW = [&](int kc, int c) {
        for (int j = 0; j < 4; ++j) {
            int seg = (wave * 4 + j) * 1024;
            int d = seg + (lane << 4);
            int row = d >> 7, chp = (d >> 4) & 7;
            gld16(wg + (size_t)row * En + kc * 64 + ((chp ^ (row & 7)) << 3),
                  (unsigned short*)((char*)&wsm[c][0][0] + seg));
        }
    };

    loadx(0);
    issueW(0, 0);
    writex(0);
    loadx(1);

    for (int kc = 0; kc < En / 64; ++kc) {
        const int c = kc & 1;
        __syncthreads();   // wsm[c] landed (vmcnt), xs[c] visible, prev reads of c^1 done
        if (kc + 1 < En / 64) {
            issueW(kc + 1, c ^ 1);
            writex(c ^ 1);
            int kn = (kc + 2 < En / 64) ? kc + 2 : En / 64 - 1;
            loadx(kn);
        }
        bf16x8 xf[2][2], wf[4][2];
        for (int i = 0; i < 2; ++i)
            for (int kk = 0; kk < 2; ++kk) {
                int row = wm + i * 16 + l15;
                int chn = (kk * 4 + quad) ^ (row & 7);
                xf[i][kk] = *(const bf16x8*)((char*)&xs[c][0][0] + row * 128 + (chn << 4));
            }
        for (int j = 0; j < 4; ++j)
            for (int kk = 0; kk < 2; ++kk) {
                int row = wn + j * 16 + l15;
                int chn = (kk * 4 + quad) ^ (row & 7);
                wf[j][kk] = *(const bf16x8*)((char*)&wsm[c][0][0] + row * 128 + (chn << 4));
            }
        if (gy != 2) {
            for (int kk = 0; kk < 2; ++kk)
                for (int i = 0; i < 2; ++i)
                    for (int j = 0; j < 4; ++j)
                        acc[i][j] = MFMA16(xf[i][kk], wf[j][kk], acc[i][j]);
        } else {
            for (int kk = 0; kk < 2; ++kk)
                for (int i = 0; i < 2; ++i)
                    for (int j = 0; j < 4; ++j)
                        acc[i][j] = MFMA16(wf[j][kk], xf[i][kk], acc[i][j]);
        }
    }

    if (gy != 2) {
        unsigned short* ob = (gy == 0) ? qb : kb;
        const float osc = (gy == 0) ? CSCALE : 1.0f;
        for (int i = 0; i < 2; ++i) {
            int rowb = m0 + wm + i * 16 + quad * 4;
            for (int j = 0; j < 4; ++j) {
                int col = wn + j * 16 + l15;
                for (int r = 0; r < 4; ++r)
                    ob[(size_t)(rowb + r) * Hn + col] = f2bf(acc[i][j][r] * osc);
            }
        }
    } else {
        for (int j = 0; j < 4; ++j) {
            int hb = wn + j * 16 + quad * 4;
            for (int i = 0; i < 2; ++i) {
                int sp = m0 + wm + i * 16 + l15;
                int bb = sp >> 12, ss = sp & 4095;
                for (int r = 0; r < 4; ++r)
                    vbT[((size_t)(bb * 128 + hb + r)) * Sn + ss] = f2bf(acc[i][j][r]);
            }
        }
    }
}

// ---------------- attention: grid-chunked, register-direct K/V, barrier-free k-loop ----------------
// grid (128 qt, 4 ch, B), block 256 = 2 pairs(p=k-split) x 2 q-groups(g).
// Chunk = 32 k-tiles of 32 keys; pair p does local tiles p, p+2, ...
// K/V frags load global->VGPR (double-buffered). Partial (O fp32, m, l) to ws when nch>1.
__global__ __launch_bounds__(256, 3) void attn_kernel(
    const unsigned short* __restrict__ qb, const unsigned short* __restrict__ kb,
    const unsigned short* __restrict__ vbT, float* __restrict__ out,
    float* __restrict__ part)
{
    __shared__ unsigned short ps[4][16][36];   // per-wave P strip [q][key]
    __shared__ float mo[2][128][17];           // pair-merge overlay (g, h, q)
    __shared__ float ml[2][2][16];

    const int qt = blockIdx.x;
    const int ch = blockIdx.y;
    const int b  = blockIdx.z;
    const int nkt = qt + 1;
    const int nch = (nkt + 31) >> 5;
    if (ch >= nch) return;
    const int c0 = ch * 32;
    const int nloc = min(32, nkt - c0);
    const int q0 = qt * 32;

    const int tid = threadIdx.x;
    const int lane = tid & 63, wave = tid >> 6;
    const int l15 = lane & 15, quad = lane >> 4;
    const int g = wave & 1;
    const int p = wave >> 1;

    const unsigned short* qg = qb + (size_t)(b * Sn + q0) * Hn;
    bf16x8 qf[4];
    for (int f = 0; f < 4; ++f)
        qf[f] = *(const bf16x8*)&qg[(g * 16 + l15) * Hn + f * 32 + quad * 8];

    f32x4 o[8] = {};
    float m_r = -INFINITY, l_r = 0.f;

    const unsigned short* kA = kb + (size_t)b * Sn * Hn + l15 * 128 + quad * 8;
    const unsigned short* vA = vbT + (size_t)b * 128 * Sn + (size_t)l15 * 4096 + quad * 8;
    unsigned short* psrow = &ps[wave][l15][0];

    bf16x8 kf[2][8], vf[2][8];
    auto loadKV = [&](int gt, int buf) {
        for (int nt = 0; nt < 2; ++nt)
            for (int kk = 0; kk < 4; ++kk)
                kf[buf][nt * 4 + kk] = *(const bf16x8*)(kA + (size_t)gt * 4096 + nt * 2048 + kk * 32);
        for (int t = 0; t < 8; ++t)
            vf[buf][t] = *(const bf16x8*)(vA + (size_t)t * 65536 + gt * 32);
    };

    if (p < nloc) loadKV(c0 + p, 0);
    int buf = 0;
    for (int t_loc = p; t_loc < nloc; t_loc += 2, buf ^= 1) {
        if (t_loc + 2 < nloc) loadKV(c0 + t_loc + 2, buf ^ 1);
        const int gt = c0 + t_loc;

        float u[2][4];
        for (int nt = 0; nt < 2; ++nt) {
            f32x4 s = {};
            for (int kk = 0; kk < 4; ++kk) s = MFMA16(kf[buf][nt * 4 + kk], qf[kk], s);
            for (int r = 0; r < 4; ++r) u[nt][r] = s[r];
        }
        if (gt == qt) {   // diagonal tile
            int qq = g * 16 + l15;
            for (int nt = 0; nt < 2; ++nt)
                for (int r = 0; r < 4; ++r)
                    if (nt * 16 + quad * 4 + r > qq) u[nt][r] = -INFINITY;
        }
        float mx = -INFINITY;
        for (int nt = 0; nt < 2; ++nt)
            for (int r = 0; r < 4; ++r) mx = fmaxf(mx, u[nt][r]);
        mx = fmaxf(mx, __shfl_xor(mx, 16));
        mx = fmaxf(mx, __shfl_xor(mx, 32));
        float mn = fmaxf(m_r, mx);
        float alpha = exp2f(m_r - mn);
        m_r = mn;
        float sum = 0.f;
        for (int nt = 0; nt < 2; ++nt)
            for (int r = 0; r < 4; ++r) {
                float pv = exp2f(u[nt][r] - mn);
                u[nt][r] = pv;
                sum += pv;
            }
        sum += __shfl_xor(sum, 16);
        sum += __shfl_xor(sum, 32);
        l_r = l_r * alpha + sum;

        for (int nt = 0; nt < 2; ++nt) {
            uint2 w2 = { pk2(u[nt][0], u[nt][1]), pk2(u[nt][2], u[nt][3]) };
            *(uint2*)&psrow[nt * 16 + quad * 4] = w2;
        }
        for (int t = 0; t < 8; ++t) o[t] *= alpha;

        bf16x8 pf = *(const bf16x8*)&psrow[quad * 8];
        for (int t = 0; t < 8; ++t)
            o[t] = MFMA16(vf[buf][t], pf, o[t]);
    }

    // merge the two k-split pairs
    __syncthreads();
    if (p == 1) {
        for (int t = 0; t < 8; ++t)
            for (int r = 0; r < 4; ++r)
                mo[g][t * 16 + quad * 4 + r][l15] = o[t][r];
        if (quad == 0) {
            ml[g][0][l15] = m_r;
            ml[g][1][l15] = l_r;
        }
    }
    __syncthreads();
    if (p == 0) {
        float m1 = ml[g][0][l15];
        float l1 = ml[g][1][l15];
        float M = fmaxf(m_r, m1);
        float w0 = exp2f(m_r - M);
        float w1 = exp2f(m1 - M);
        float L = w0 * l_r + w1 * l1;
        if (nch == 1) {
            float inv = 1.0f / L;
            float* og = out + (size_t)(b * Sn + q0 + g * 16 + l15) * Hn;
            for (int t = 0; t < 8; ++t) {
                float4 st;
                st.x = (w0 * o[t][0] + w1 * mo[g][t * 16 + quad * 4 + 0][l15]) * inv;
                st.y = (w0 * o[t][1] + w1 * mo[g][t * 16 + quad * 4 + 1][l15]) * inv;
                st.z = (w0 * o[t][2] + w1 * mo[g][t * 16 + quad * 4 + 2][l15]) * inv;
                st.w = (w0 * o[t][3] + w1 * mo[g][t * 16 + quad * 4 + 3][l15]) * inv;
                *(float4*)&og[t * 16 + quad * 4] = st;
            }
        } else {
            float* P = part + (size_t)(b * SLOTS_PER_B + slot_base(qt) + ch) * SLOT_F;
            int q = g * 16 + l15;
            for (int t = 0; t < 8; ++t) {
                float4 st;
                st.x = w0 * o[t][0] + w1 * mo[g][t * 16 + quad * 4 + 0][l15];
                st.y = w0 * o[t][1] + w1 * mo[g][t * 16 + quad * 4 + 1][l15];
                st.z = w0 * o[t][2] + w1 * mo[g][t * 16 + quad * 4 + 2][l15];
                st.w = w0 * o[t][3] + w1 * mo[g][t * 16 + quad * 4 + 3][l15];
                *(float4*)&P[q * 128 + t * 16 + quad * 4] = st;
            }
            if (quad == 0) {
                P[4096 + q] = M;
                P[4128 + q] = L;
            }
        }
    }
}

// ---------------- merge partials for qt >= 32 ----------------
// grid (96, B), 256 thr: thread = (q = tid>>3, 16 h at (tid&7)*16)
__global__ __launch_bounds__(256) void merge_kernel(
    const float* __restrict__ part, float* __restrict__ out)
{
    const int qt = 32 + blockIdx.x;
    const int b = blockIdx.y;
    const int nch = (qt >> 5) + 1;
    const float* P0 = part + (size_t)(b * SLOTS_PER_B + slot_base(qt)) * SLOT_F;
    const int q = threadIdx.x >> 3;
    const int h0 = (threadIdx.x & 7) * 16;

    float m[4], w[4];
    float M = -INFINITY;
    for (int c = 0; c < nch; ++c) {
        m[c] = P0[(size_t)c * SLOT_F + 4096 + q];
        M = fmaxf(M, m[c]);
    }
    float L = 0.f;
    for (int c = 0; c < nch; ++c) {
        w[c] = exp2f(m[c] - M);
        L += w[c] * P0[(size_t)c * SLOT_F + 4128 + q];
    }
    float inv = 1.0f / L;

    float acc[16] = {};
    for (int c = 0; c < nch; ++c) {
        const float* Pq = P0 + (size_t)c * SLOT_F + q * 128 + h0;
        for (int j = 0; j < 4; ++j) {
            float4 v = *(const float4*)&Pq[j * 4];
            acc[j * 4 + 0] += w[c] * v.x;
            acc[j * 4 + 1] += w[c] * v.y;
            acc[j * 4 + 2] += w[c] * v.z;
            acc[j * 4 + 3] += w[c] * v.w;
        }
    }
    float* og = out + (size_t)(b * Sn + qt * 32 + q) * Hn + h0;
    for (int j = 0; j < 4; ++j) {
        float4 st = { acc[j * 4 + 0] * inv, acc[j * 4 + 1] * inv,
                      acc[j * 4 + 2] * inv, acc[j * 4 + 3] * inv };
        *(float4*)&og[j * 4] = st;
    }
}

extern "C" void kernel_launch(void* const* d_in, const int* in_sizes, int n_in,
                              void* d_out, int out_size, void* d_ws, size_t ws_size,
                              hipStream_t stream)
{
    const float* x  = (const float*)d_in[0];
    const float* Wk = (const float*)d_in[1];
    const float* Wq = (const float*)d_in[2];
    const float* Wv = (const float*)d_in[3];
    float* out = (float*)d_out;

    unsigned short* qbuf  = (unsigned short*)d_ws;                  // 4 MB (pre-scaled)
    unsigned short* kbuf  = qbuf + (size_t)Bn * Sn * Hn;            // 4 MB
    unsigned short* vbufT = kbuf + (size_t)Bn * Sn * Hn;            // 4 MB, [b][h][s]
    unsigned short* wb    = vbufT + (size_t)Bn * Sn * Hn;           // 0.75 MB bf16 W
    float* part = (float*)(wb + (size_t)3 * Hn * En);               // 21.3 MB partials

    prep_kernel<<<96, 256, 0, stream>>>(Wk, Wq, Wv, wb);
    proj_kernel<<<dim3(Bn * Sn / 64, 3), 256, 0, stream>>>(x, wb, qbuf, kbuf, vbufT);
    attn_kernel<<<dim3(128, 4, Bn), 256, 0, stream>>>(qbuf, kbuf, vbufT, out, part);
    merge_kernel<<<dim3(96, Bn), 256, 0, stream>>>(part, out);
}

// Round 8
// 177.590 us; speedup vs baseline: 3.3257x; 3.3257x over previous
//
#include <hip/hip_runtime.h>

typedef short bf16x8 __attribute__((ext_vector_type(8)));
typedef float f32x4 __attribute__((ext_vector_type(4)));

#define MFMA16(a, b, c) __builtin_amdgcn_mfma_f32_16x16x32_bf16(a, b, c, 0, 0, 0)

constexpr int Bn = 4, Sn = 4096, En = 1024, Hn = 128;
constexpr float CSCALE = 1.44269504089f * 0.03125f;   // log2(e) * E^-0.5

// attn partials: qt64 uses ceil((qt64+1)/16) chunks; slot base = prefix sum
__device__ inline int sb64(int qt) {
    int a = qt >> 4, r = qt & 15;
    return 8 * a * (a + 1) + r * (a + 1);
}
constexpr int SB = 160;            // sb64(64)
constexpr int SLOT_F = 8320;       // 64*128 O + 64 m + 64 l floats

__device__ inline unsigned short f2bf(float f) {
    unsigned int u = __builtin_bit_cast(unsigned int, f);
    u += 0x7fff + ((u >> 16) & 1);
    return (unsigned short)(u >> 16);
}

__device__ inline unsigned int pk2(float a, float b) {
    unsigned int ua = __builtin_bit_cast(unsigned int, a) + 0x8000u;
    unsigned int ub = __builtin_bit_cast(unsigned int, b) + 0x8000u;
    return __builtin_amdgcn_perm(ub, ua, 0x07060302u);
}

__device__ inline void gld16(const unsigned short* g, unsigned short* l) {
    __builtin_amdgcn_global_load_lds((const __attribute__((address_space(1))) void*)g,
                                     (__attribute__((address_space(3))) void*)l, 16, 0, 0);
}

// ---------------- prep: W fp32 -> bf16, [q,k,v][h][E] ----------------
__global__ __launch_bounds__(256) void prep_kernel(
    const float* __restrict__ Wk, const float* __restrict__ Wq, const float* __restrict__ Wv,
    unsigned short* __restrict__ wb)
{
    int gy = blockIdx.x >> 5;
    const float* src = (gy == 0) ? Wq : (gy == 1) ? Wk : Wv;
    unsigned short* dst = wb + (size_t)gy * Hn * En;
    int t = (blockIdx.x & 31) * 256 + threadIdx.x;
    const float4* s4 = (const float4*)src;
    for (int i = 0; i < 4; ++i) {
        float4 v = s4[(size_t)t * 4 + i];
        uint2 w2 = { pk2(v.x, v.y), pk2(v.z, v.w) };
        *(uint2*)&dst[(size_t)t * 16 + i * 4] = w2;
    }
}

// ---------------- QKV projection (R7 structure — async bf16 W staging) ----------------
__global__ __launch_bounds__(256, 3) void proj_kernel(
    const float* __restrict__ x, const unsigned short* __restrict__ wb,
    unsigned short* __restrict__ qb, unsigned short* __restrict__ kb,
    unsigned short* __restrict__ vbT)
{
    __shared__ __align__(16) unsigned short xs[2][64][64];
    __shared__ __align__(16) unsigned short wsm[2][128][64];

    const int gy = blockIdx.y;
    const unsigned short* wg = wb + (size_t)gy * Hn * En;

    const int m0 = blockIdx.x * 64;
    const int tid = threadIdx.x;
    const int lane = tid & 63, wave = tid >> 6;
    const int l15 = lane & 15, quad = lane >> 4;
    const int wm = (wave & 1) * 32;
    const int wn = (wave >> 1) * 64;

    f32x4 acc[2][4] = {};
    float4 xp[4];

    auto loadx = [&](int kc) {
        for (int p4 = 0; p4 < 4; ++p4) {
            int i = p4 * 256 + tid, row = i >> 4, c4 = (i & 15) * 4;
            xp[p4] = *(const float4*)&x[(size_t)(m0 + row) * En + kc * 64 + c4];
        }
    };
    auto writex = [&](int c) {
        for (int p4 = 0; p4 < 4; ++p4) {
            int i = p4 * 256 + tid, row = i >> 4, hc = i & 15;
            uint2 w2 = { pk2(xp[p4].x, xp[p4].y), pk2(xp[p4].z, xp[p4].w) };
            *(uint2*)((char*)&xs[c][0][0] + row * 128 + (((hc >> 1) ^ (row & 7)) << 4) + ((hc & 1) << 3)) = w2;
        }
    };
    auto issueW = [&](int kc, int c) {
        for (int j = 0; j < 4; ++j) {
            int seg = (wave * 4 + j) * 1024;
            int d = seg + (lane << 4);
            int row = d >> 7, chp = (d >> 4) & 7;
            gld16(wg + (size_t)row * En + kc * 64 + ((chp ^ (row & 7)) << 3),
                  (unsigned short*)((char*)&wsm[c][0][0] + seg));
        }
    };

    loadx(0);
    issueW(0, 0);
    writex(0);
    loadx(1);

    for (int kc = 0; kc < En / 64; ++kc) {
        const int c = kc & 1;
        __syncthreads();
        if (kc + 1 < En / 64) {
            issueW(kc + 1, c ^ 1);
            writex(c ^ 1);
            int kn = (kc + 2 < En / 64) ? kc + 2 : En / 64 - 1;
            loadx(kn);
        }
        bf16x8 xf[2][2], wf[4][2];
        for (int i = 0; i < 2; ++i)
            for (int kk = 0; kk < 2; ++kk) {
                int row = wm + i * 16 + l15;
                int chn = (kk * 4 + quad) ^ (row & 7);
                xf[i][kk] = *(const bf16x8*)((char*)&xs[c][0][0] + row * 128 + (chn << 4));
            }
        for (int j = 0; j < 4; ++j)
            for (int kk = 0; kk < 2; ++kk) {
                int row = wn + j * 16 + l15;
                int chn = (kk * 4 + quad) ^ (row & 7);
                wf[j][kk] = *(const bf16x8*)((char*)&wsm[c][0][0] + row * 128 + (chn << 4));
            }
        if (gy != 2) {
            for (int kk = 0; kk < 2; ++kk)
                for (int i = 0; i < 2; ++i)
                    for (int j = 0; j < 4; ++j)
                        acc[i][j] = MFMA16(xf[i][kk], wf[j][kk], acc[i][j]);
        } else {
            for (int kk = 0; kk < 2; ++kk)
                for (int i = 0; i < 2; ++i)
                    for (int j = 0; j < 4; ++j)
                        acc[i][j] = MFMA16(wf[j][kk], xf[i][kk], acc[i][j]);
        }
    }

    if (gy != 2) {
        unsigned short* ob = (gy == 0) ? qb : kb;
        const float osc = (gy == 0) ? CSCALE : 1.0f;
        for (int i = 0; i < 2; ++i) {
            int rowb = m0 + wm + i * 16 + quad * 4;
            for (int j = 0; j < 4; ++j) {
                int col = wn + j * 16 + l15;
                for (int r = 0; r < 4; ++r)
                    ob[(size_t)(rowb + r) * Hn + col] = f2bf(acc[i][j][r] * osc);
            }
        }
    } else {
        for (int j = 0; j < 4; ++j) {
            int hb = wn + j * 16 + quad * 4;
            for (int i = 0; i < 2; ++i) {
                int sp = m0 + wm + i * 16 + l15;
                int bb = sp >> 12, ss = sp & 4095;
                for (int r = 0; r < 4; ++r)
                    vbT[((size_t)(bb * 128 + hb + r)) * Sn + ss] = f2bf(acc[i][j][r]);
            }
        }
    }
}

// ---------------- attention: 64-row q-tiles, grid K-chunking, LDS-shared staging ----------------
// grid (64 qt, 4 ch, B), block 256 = 4 waves; wave w owns q-rows q0+w*16..+15.
// Chunk = up to 16 BK=64 k-tiles. All waves share one K/V LDS tile (fetch-efficient).
// Per-lane online softmax (S^T = K Q^T: q on lane&15). Partials to ws when nch>1.
__global__ __launch_bounds__(256, 3) void attn_kernel(
    const unsigned short* __restrict__ qb, const unsigned short* __restrict__ kb,
    const unsigned short* __restrict__ vbT, float* __restrict__ out,
    float* __restrict__ part)
{
    __shared__ unsigned short ks[64][132];    // K tile [key][h]
    __shared__ unsigned short vt[128][68];    // V^T [h][key]
    __shared__ unsigned short ps[4][16][72];  // per-wave P strip [q][key]

    const int qt = 63 - (int)blockIdx.x;      // longest first
    const int ch = blockIdx.y;
    const int b  = blockIdx.z;
    const int T  = qt + 1;                    // total k-tiles for this q-tile
    const int nch = (T + 15) >> 4;
    if (ch >= nch) return;
    const int t0 = ch * 16;
    const int nloc = min(16, T - t0);
    const int q0 = qt * 64;

    const int tid = threadIdx.x;
    const int lane = tid & 63, wave = tid >> 6;
    const int l15 = lane & 15, quad = lane >> 4;

    const unsigned short* qg = qb + (size_t)(b * Sn + q0) * Hn;
    bf16x8 qf[4];
    for (int f = 0; f < 4; ++f)
        qf[f] = *(const bf16x8*)&qg[(wave * 16 + l15) * Hn + f * 32 + quad * 8];

    f32x4 o[8] = {};             // O^T: h = t*16+quad*4+r, q = l15 (this wave's row group)
    float m_r = -INFINITY, l_r = 0.f;

    const unsigned short* kg = kb + (size_t)b * Sn * Hn;
    const unsigned short* vg = vbT + (size_t)b * 128 * Sn;
    unsigned short* psrow = &ps[wave][l15][0];

    bf16x8 kreg[4], vreg[4];
    auto loadKV = [&](int gt) {
        int kt0 = gt * 64;
        for (int p4 = 0; p4 < 4; ++p4) {
            int i = p4 * 256 + tid;
            kreg[p4] = *(const bf16x8*)&kg[(size_t)(kt0 + (i >> 4)) * Hn + (i & 15) * 8];
            vreg[p4] = *(const bf16x8*)&vg[(size_t)(i >> 3) * Sn + kt0 + (i & 7) * 8];
        }
    };

    loadKV(t0);
    for (int tl = 0; tl < nloc; ++tl) {
        const int gt = t0 + tl;
        for (int p4 = 0; p4 < 4; ++p4) {
            int i = p4 * 256 + tid;
            *(bf16x8*)&ks[i >> 4][(i & 15) * 8] = kreg[p4];
            *(bf16x8*)&vt[i >> 3][(i & 7) * 8] = vreg[p4];
        }
        __syncthreads();
        if (tl + 1 < nloc) loadKV(gt + 1);

        // S^T: A = K (m=key), B = Q (n=q). u[nt][r]: key = gt*64+nt*16+quad*4+r, q = l15
        float u[4][4];
        for (int nt = 0; nt < 4; ++nt) {
            f32x4 s = {};
            for (int kk = 0; kk < 4; ++kk) {
                bf16x8 kf = *(const bf16x8*)&ks[nt * 16 + l15][kk * 32 + quad * 8];
                s = MFMA16(kf, qf[kk], s);
            }
            for (int r = 0; r < 4; ++r) u[nt][r] = s[r];
        }
        if (gt == qt) {   // only the last tile intersects the diagonal
            int qq = wave * 16 + l15;
            for (int nt = 0; nt < 4; ++nt)
                for (int r = 0; r < 4; ++r)
                    if (nt * 16 + quad * 4 + r > qq) u[nt][r] = -INFINITY;
        }
        // per-lane online softmax (log2 domain; CSCALE folded into q at projection)
        float mx = -INFINITY;
        for (int nt = 0; nt < 4; ++nt)
            for (int r = 0; r < 4; ++r) mx = fmaxf(mx, u[nt][r]);
        mx = fmaxf(mx, __shfl_xor(mx, 16));
        mx = fmaxf(mx, __shfl_xor(mx, 32));
        float mn = fmaxf(m_r, mx);
        float alpha = exp2f(m_r - mn);
        m_r = mn;
        float sum = 0.f;
        for (int nt = 0; nt < 4; ++nt)
            for (int r = 0; r < 4; ++r) {
                float pv = exp2f(u[nt][r] - mn);
                u[nt][r] = pv;
                sum += pv;
            }
        sum += __shfl_xor(sum, 16);
        sum += __shfl_xor(sum, 32);
        l_r = l_r * alpha + sum;

        // P -> LDS [q][key] (same-wave strip; no barrier needed)
        for (int nt = 0; nt < 4; ++nt) {
            uint2 w2 = { pk2(u[nt][0], u[nt][1]), pk2(u[nt][2], u[nt][3]) };
            *(uint2*)&psrow[nt * 16 + quad * 4] = w2;
        }
        for (int t = 0; t < 8; ++t) o[t] *= alpha;

        // O^T += V^T P^T
        for (int k2 = 0; k2 < 2; ++k2) {
            bf16x8 pf = *(const bf16x8*)&psrow[k2 * 32 + quad * 8];
            for (int t = 0; t < 8; ++t) {
                bf16x8 vf = *(const bf16x8*)&vt[t * 16 + l15][k2 * 32 + quad * 8];
                o[t] = MFMA16(vf, pf, o[t]);
            }
        }
        __syncthreads();   // protect ks/vt before next iteration's writes
    }

    if (nch == 1) {
        float inv = 1.0f / l_r;
        float* og = out + (size_t)(b * Sn + q0 + wave * 16 + l15) * Hn;
        for (int t = 0; t < 8; ++t) {
            float4 st = { o[t][0] * inv, o[t][1] * inv, o[t][2] * inv, o[t][3] * inv };
            *(float4*)&og[t * 16 + quad * 4] = st;
        }
    } else {
        float* P = part + (size_t)(b * SB + sb64(qt) + ch) * SLOT_F;
        int q = wave * 16 + l15;
        for (int t = 0; t < 8; ++t) {
            float4 st = { o[t][0], o[t][1], o[t][2], o[t][3] };
            *(float4*)&P[q * 128 + t * 16 + quad * 4] = st;
        }
        if (quad == 0) {
            P[8192 + q] = m_r;
            P[8256 + q] = l_r;
        }
    }
}

// ---------------- merge partials for qt >= 16 ----------------
// grid (48, B), 256 thr: q = tid>>2 (64 rows), h0 = (tid&3)*32 (32 h each)
__global__ __launch_bounds__(256) void merge_kernel(
    const float* __restrict__ part, float* __restrict__ out)
{
    const int qt = 16 + blockIdx.x;
    const int b = blockIdx.y;
    const int nch = (qt + 16) >> 4;
    const float* P0 = part + (size_t)(b * SB + sb64(qt)) * SLOT_F;
    const int q = threadIdx.x >> 2;
    const int h0 = (threadIdx.x & 3) * 32;

    float m[4], w[4];
    float M = -INFINITY;
    for (int c = 0; c < nch; ++c) {
        m[c] = P0[(size_t)c * SLOT_F + 8192 + q];
        M = fmaxf(M, m[c]);
    }
    float L = 0.f;
    for (int c = 0; c < nch; ++c) {
        w[c] = exp2f(m[c] - M);
        L += w[c] * P0[(size_t)c * SLOT_F + 8256 + q];
    }
    float inv = 1.0f / L;

    float acc[32] = {};
    for (int c = 0; c < nch; ++c) {
        const float* Pq = P0 + (size_t)c * SLOT_F + q * 128 + h0;
        for (int j = 0; j < 8; ++j) {
            float4 v = *(const float4*)&Pq[j * 4];
            acc[j * 4 + 0] += w[c] * v.x;
            acc[j * 4 + 1] += w[c] * v.y;
            acc[j * 4 + 2] += w[c] * v.z;
            acc[j * 4 + 3] += w[c] * v.w;
        }
    }
    float* og = out + (size_t)(b * Sn + qt * 64 + q) * Hn + h0;
    for (int j = 0; j < 8; ++j) {
        float4 st = { acc[j * 4 + 0] * inv, acc[j * 4 + 1] * inv,
                      acc[j * 4 + 2] * inv, acc[j * 4 + 3] * inv };
        *(float4*)&og[j * 4] = st;
    }
}

extern "C" void kernel_launch(void* const* d_in, const int* in_sizes, int n_in,
                              void* d_out, int out_size, void* d_ws, size_t ws_size,
                              hipStream_t stream)
{
    const float* x  = (const float*)d_in[0];
    const float* Wk = (const float*)d_in[1];
    const float* Wq = (const float*)d_in[2];
    const float* Wv = (const float*)d_in[3];
    float* out = (float*)d_out;

    unsigned short* qbuf  = (unsigned short*)d_ws;                  // 4 MB (pre-scaled)
    unsigned short* kbuf  = qbuf + (size_t)Bn * Sn * Hn;            // 4 MB
    unsigned short* vbufT = kbuf + (size_t)Bn * Sn * Hn;            // 4 MB, [b][h][s]
    unsigned short* wb    = vbufT + (size_t)Bn * Sn * Hn;           // 0.75 MB bf16 W
    float* part = (float*)(wb + (size_t)3 * Hn * En);               // 21.3 MB partials

    prep_kernel<<<96, 256, 0, stream>>>(Wk, Wq, Wv, wb);
    proj_kernel<<<dim3(Bn * Sn / 64, 3), 256, 0, stream>>>(x, wb, qbuf, kbuf, vbufT);
    attn_kernel<<<dim3(64, 4, Bn), 256, 0, stream>>>(qbuf, kbuf, vbufT, out, part);
    merge_kernel<<<dim3(48, Bn), 256, 0, stream>>>(part, out);
}